// Round 6
// baseline (8581.845 us; speedup 1.0000x reference)
//
#include <hip/hip_runtime.h>
#include <math.h>

typedef unsigned short u16;
typedef unsigned int   u32;
typedef __bf16 bf16x8 __attribute__((ext_vector_type(8)));
typedef float  f32x4  __attribute__((ext_vector_type(4)));

#define BB 256
#define TT 256
#define HD 256
#define ED 128

/* ws layout (u32 units):
   [0, H_U32)            : h ping-pong, packed bf16 hi|lo<<16  [10][2][256][256]
   [H_U32, +FLG_U32)     : flags [10][256][2] padded x4
   [XP_OFF, +XP_U32)     : packed x  [256][256][8]
   [WT_OFF, ...)         : fragment-ordered bf16 weights (r4/r5 layout)       */
#define H_U32   (10 * 2 * BB * HD)          /* 1,310,720 */
#define FLG_U32 (10 * TT * 2 * 4)           /*    20,480 */
#define XP_OFF  (H_U32 + FLG_U32)
#define XP_U32  (BB * TT * 8)               /*   524,288 */
#define WT_OFF  (XP_OFF + XP_U32)

__constant__ size_t g_woff[10] = {0ul,589824ul,1638400ul,2686976ul,3735552ul,
                                  4784128ul,5177344ul,5439488ul,5701632ul,5963776ul};
__constant__ int g_cb[11] = {0,73728,204800,335872,466944,598016,
                             647168,679936,712704,745472,778240};

__device__ __forceinline__ u16 f2bf_hi(float f) {
    u32 u = __float_as_uint(f);
    u32 r = (u + 0x7FFFu + ((u >> 16) & 1u)) >> 16;
    return (u16)r;
}
__device__ __forceinline__ float bf2f(u16 h) { return __uint_as_float(((u32)h) << 16); }
__device__ __forceinline__ float sigmoidf_(float v) { return 1.0f / (1.0f + expf(-v)); }

__global__ __launch_bounds__(256) void zero_state(u32* wsd) {
    const int n = H_U32 + FLG_U32;
    for (int i = blockIdx.x * blockDim.x + threadIdx.x; i < n; i += gridDim.x * blockDim.x)
        wsd[i] = 0u;
}

__global__ __launch_bounds__(256) void conv_x(const float* __restrict__ x, u32* __restrict__ wsd) {
    u32* xp = wsd + XP_OFF;
    for (int i = blockIdx.x * blockDim.x + threadIdx.x; i < XP_U32; i += gridDim.x * blockDim.x) {
        float v = x[i];
        u16 hi = f2bf_hi(v);
        u16 lo = f2bf_hi(v - bf2f(hi));
        xp[i] = (u32)hi | ((u32)lo << 16);
    }
}

/* weights -> bf16 hi/lo, MFMA fragment order (proven r4/r5 layout) */
__global__ __launch_bounds__(256) void conv_all(
    const float* __restrict__ w_ih0_1, const float* __restrict__ w_ihr_1,
    const float* __restrict__ w_hh_1,
    const float* __restrict__ w_ih0_2, const float* __restrict__ w_ihr_2,
    const float* __restrict__ w_hh_2,
    u32* __restrict__ wsd)
{
    __bf16* dst0 = (__bf16*)(wsd + WT_OFF);
    const int nch = 778240;
    for (int ci = blockIdx.x * blockDim.x + threadIdx.x; ci < nch;
         ci += gridDim.x * blockDim.x) {
        int l = 0;
        while (ci >= g_cb[l + 1]) ++l;
        int di = ci - g_cb[l];

        const int hd  = (l < 5) ? 256 : 128;
        const int din = (l == 0) ? 32 : ((l < 6) ? 256 : 128);
        const int xw  = (l == 0) ? 8 : din;
        const int Kp  = din + hd;
        const int nk  = Kp >> 5;

        const float *wih, *whh; int wihld, whhld;
        if (l == 0)      { wih = w_ih0_1;                                whh = w_hh_1;
                           wihld = 8;   whhld = 256; }
        else if (l < 5)  { wih = w_ihr_1 + (size_t)(l - 1) * 1024 * 256; whh = w_hh_1 + (size_t)l * 1024 * 256;
                           wihld = 256; whhld = 256; }
        else if (l == 5) { wih = w_ih0_2;                                whh = w_hh_2;
                           wihld = 256; whhld = 128; }
        else             { wih = w_ihr_2 + (size_t)(l - 6) * 512 * 128;  whh = w_hh_2 + (size_t)(l - 5) * 512 * 128;
                           wihld = 128; whhld = 128; }

        int lane = di & 63;
        int rem  = di >> 6;
        int kt   = rem % nk;
        int rem2 = rem / nk;
        int p    = rem2 & 1;
        int g    = (rem2 >> 1) & 3;
        int jt   = rem2 >> 3;
        int r15  = lane & 15, kq = lane >> 4;
        int row  = g * hd + jt * 16 + r15;

        bf16x8 o8;
        #pragma unroll
        for (int e = 0; e < 8; ++e) {
            int k = kt * 32 + kq * 8 + e;
            float v = 0.0f;
            if (k < xw) v = wih[(size_t)row * wihld + k];
            else if (k >= din && k < Kp) v = whh[(size_t)row * whhld + (k - din)];
            __bf16 h = (__bf16)v;
            o8[e] = p ? (__bf16)(v - (float)h) : h;
        }
        *(bf16x8*)(dst0 + g_woff[l] + (size_t)di * 8) = o8;
    }
}

__device__ __forceinline__ void pollf(const u32* __restrict__ flg, int l_, int t_, int bt, u32 target) {
    const u32* p = flg + ((size_t)(l_ * TT + t_) * 2 + bt) * 4;
    for (int it = 0; it < (1 << 17); ++it) {
        if (__hip_atomic_load(p, __ATOMIC_RELAXED, __HIP_MEMORY_SCOPE_AGENT) >= target) return;
        __builtin_amdgcn_s_sleep(1);
    }
}

__device__ __forceinline__ void unpack8(const uint4& a, const uint4& b, bf16x8& bh, bf16x8& bl) {
    union { u32 u[4]; bf16x8 v; } H, L;
    H.u[0] = (a.x & 0xFFFFu) | (a.y << 16);
    H.u[1] = (a.z & 0xFFFFu) | (a.w << 16);
    H.u[2] = (b.x & 0xFFFFu) | (b.y << 16);
    H.u[3] = (b.z & 0xFFFFu) | (b.w << 16);
    L.u[0] = (a.x >> 16) | (a.y & 0xFFFF0000u);
    L.u[1] = (a.z >> 16) | (a.w & 0xFFFF0000u);
    L.u[2] = (b.x >> 16) | (b.y & 0xFFFF0000u);
    L.u[3] = (b.z >> 16) | (b.w & 0xFFFF0000u);
    bh = H.v; bl = L.v;
}

__device__ __forceinline__ void mfma12(const u16* __restrict__ A_lds,
    int oh0,int oh1,int oh2,int oh3,int ol0,int ol1,int ol2,int ol3,int kof,
    const bf16x8& bh, const bf16x8& bl,
    f32x4& acc0, f32x4& acc1, f32x4& acc2, f32x4& acc3)
{
    bf16x8 a0h = *(const bf16x8*)&A_lds[oh0 + kof];
    bf16x8 a1h = *(const bf16x8*)&A_lds[oh1 + kof];
    bf16x8 a2h = *(const bf16x8*)&A_lds[oh2 + kof];
    bf16x8 a3h = *(const bf16x8*)&A_lds[oh3 + kof];
    acc0 = __builtin_amdgcn_mfma_f32_16x16x32_bf16(a0h, bh, acc0, 0,0,0);
    acc1 = __builtin_amdgcn_mfma_f32_16x16x32_bf16(a1h, bh, acc1, 0,0,0);
    acc2 = __builtin_amdgcn_mfma_f32_16x16x32_bf16(a2h, bh, acc2, 0,0,0);
    acc3 = __builtin_amdgcn_mfma_f32_16x16x32_bf16(a3h, bh, acc3, 0,0,0);
    acc0 = __builtin_amdgcn_mfma_f32_16x16x32_bf16(a0h, bl, acc0, 0,0,0);
    acc1 = __builtin_amdgcn_mfma_f32_16x16x32_bf16(a1h, bl, acc1, 0,0,0);
    acc2 = __builtin_amdgcn_mfma_f32_16x16x32_bf16(a2h, bl, acc2, 0,0,0);
    acc3 = __builtin_amdgcn_mfma_f32_16x16x32_bf16(a3h, bl, acc3, 0,0,0);
    bf16x8 a0l = *(const bf16x8*)&A_lds[ol0 + kof];
    bf16x8 a1l = *(const bf16x8*)&A_lds[ol1 + kof];
    bf16x8 a2l = *(const bf16x8*)&A_lds[ol2 + kof];
    bf16x8 a3l = *(const bf16x8*)&A_lds[ol3 + kof];
    acc0 = __builtin_amdgcn_mfma_f32_16x16x32_bf16(a0l, bh, acc0, 0,0,0);
    acc1 = __builtin_amdgcn_mfma_f32_16x16x32_bf16(a1l, bh, acc1, 0,0,0);
    acc2 = __builtin_amdgcn_mfma_f32_16x16x32_bf16(a2l, bh, acc2, 0,0,0);
    acc3 = __builtin_amdgcn_mfma_f32_16x16x32_bf16(a3l, bh, acc3, 0,0,0);
}

/* chunked (4-kt) double-buffered phase pipeline; all indices static after unroll */
template<int NKT, typename LD>
__device__ __forceinline__ void gemm_phase(const LD& ld, int ktBase,
    const u16* __restrict__ A_lds,
    int oh0,int oh1,int oh2,int oh3,int ol0,int ol1,int ol2,int ol3,
    f32x4& acc0, f32x4& acc1, f32x4& acc2, f32x4& acc3)
{
    constexpr int CH  = (NKT < 4) ? NKT : 4;
    constexpr int NCH = (NKT + CH - 1) / CH;
    uint4 pa[2][CH], pb[2][CH];
    #pragma unroll
    for (int i = 0; i < CH; ++i)
        if (i < NKT) ld(ktBase + i, pa[0][i], pb[0][i]);
    #pragma unroll
    for (int c = 0; c < NCH; ++c) {
        #pragma unroll
        for (int i = 0; i < CH; ++i) {
            const int kt = (c + 1) * CH + i;
            if (kt < NKT) ld(ktBase + kt, pa[(c + 1) & 1][i], pb[(c + 1) & 1][i]);
        }
        #pragma unroll
        for (int i = 0; i < CH; ++i) {
            const int kt = c * CH + i;
            if (kt < NKT) {
                bf16x8 bh, bl;
                unpack8(pa[c & 1][i], pb[c & 1][i], bh, bl);
                mfma12(A_lds, oh0,oh1,oh2,oh3, ol0,ol1,ol2,ol3,
                       (ktBase + kt) * 512, bh, bl, acc0, acc1, acc2, acc3);
            }
        }
    }
}

template<int NKI, int NKR, bool ISL0>
__device__ void run_all(
    int l, int bt,
    const u32* __restrict__ xp, const float* __restrict__ bias,
    u32* __restrict__ hbuf, u32* __restrict__ flg, float* __restrict__ out,
    const u16* __restrict__ A_lds,
    int oh0,int oh1,int oh2,int oh3,int ol0,int ol1,int ol2,int ol3,
    int brow, int j0, int kq, int hd,
    u32 tgt_lo, u32 tgt_my, u32 tgt_dn)
{
    constexpr int DIN = NKI * 32;
    const int tid = threadIdx.x;

    float bgr[4][4];
    #pragma unroll
    for (int g = 0; g < 4; ++g) {
        float4 v = *(const float4*)&bias[g * hd + j0];
        bgr[g][0] = v.x; bgr[g][1] = v.y; bgr[g][2] = v.z; bgr[g][3] = v.w;
    }

    float4 cv = make_float4(0.f, 0.f, 0.f, 0.f);

    for (int t = 0; t < TT; ++t) {
        const u32* hin   = hbuf + ((size_t)(l - 1) * 2 + (t & 1)) * (BB * HD);
        const u32* hprev = hbuf + ((size_t)l * 2 + ((t & 1) ^ 1)) * (BB * HD);
        u32*       hout  = hbuf + ((size_t)l * 2 + (t & 1)) * (BB * HD);

        /* phase-A dep (layer below, one wavefront early) + backpressure */
        if (!ISL0)            pollf(flg, l - 1, t, bt, tgt_lo);
        if (l < 9 && t >= 2)  pollf(flg, l + 1, t - 2, bt, tgt_dn);
        if (!ISL0) __builtin_amdgcn_fence(__ATOMIC_ACQUIRE, "agent");

        f32x4 acc0 = {0.f,0.f,0.f,0.f}, acc1 = {0.f,0.f,0.f,0.f};
        f32x4 acc2 = {0.f,0.f,0.f,0.f}, acc3 = {0.f,0.f,0.f,0.f};

        auto ldI = [&](int kt, uint4& A, uint4& B) {
            if constexpr (ISL0) {
                if (kq == 0) {
                    const u32* p = xp + ((size_t)brow * TT + t) * 8;
                    A = *(const uint4*)p; B = *(const uint4*)(p + 4);
                } else { A = make_uint4(0,0,0,0); B = make_uint4(0,0,0,0); }
            } else {
                const u32* p = hin + (size_t)brow * HD + kt * 32 + kq * 8;
                A = *(const uint4*)p; B = *(const uint4*)(p + 4);
            }
        };
        gemm_phase<NKI>(ldI, 0, A_lds, oh0,oh1,oh2,oh3, ol0,ol1,ol2,ol3,
                        acc0, acc1, acc2, acc3);

        /* phase-B dep: own layer, t-1 (the tight chain) — polled late */
        if (t > 0) {
            pollf(flg, l, t - 1, bt, tgt_my);
            __builtin_amdgcn_fence(__ATOMIC_ACQUIRE, "agent");
        }
        auto ldR = [&](int kt, uint4& A, uint4& B) {
            const u32* p = hprev + (size_t)brow * HD + (kt * 32 - DIN) + kq * 8;
            A = *(const uint4*)p; B = *(const uint4*)(p + 4);
        };
        gemm_phase<NKR>(ldR, NKI, A_lds, oh0,oh1,oh2,oh3, ol0,ol1,ol2,ol3,
                        acc0, acc1, acc2, acc3);

        /* epilogue: bias + activations + register c update */
        float4 hv;
        {
            float i_, f_, g_, o_;
            i_ = sigmoidf_(acc0[0] + bgr[0][0]); f_ = sigmoidf_(acc1[0] + bgr[1][0]);
            g_ = tanhf   (acc2[0] + bgr[2][0]); o_ = sigmoidf_(acc3[0] + bgr[3][0]);
            cv.x = fmaf(f_, cv.x, i_ * g_); hv.x = o_ * tanhf(cv.x);
            i_ = sigmoidf_(acc0[1] + bgr[0][1]); f_ = sigmoidf_(acc1[1] + bgr[1][1]);
            g_ = tanhf   (acc2[1] + bgr[2][1]); o_ = sigmoidf_(acc3[1] + bgr[3][1]);
            cv.y = fmaf(f_, cv.y, i_ * g_); hv.y = o_ * tanhf(cv.y);
            i_ = sigmoidf_(acc0[2] + bgr[0][2]); f_ = sigmoidf_(acc1[2] + bgr[1][2]);
            g_ = tanhf   (acc2[2] + bgr[2][2]); o_ = sigmoidf_(acc3[2] + bgr[3][2]);
            cv.z = fmaf(f_, cv.z, i_ * g_); hv.z = o_ * tanhf(cv.z);
            i_ = sigmoidf_(acc0[3] + bgr[0][3]); f_ = sigmoidf_(acc1[3] + bgr[1][3]);
            g_ = tanhf   (acc2[3] + bgr[2][3]); o_ = sigmoidf_(acc3[3] + bgr[3][3]);
            cv.w = fmaf(f_, cv.w, i_ * g_); hv.w = o_ * tanhf(cv.w);
        }

        /* pack h -> u32 (hi | lo<<16), write-through agent atomic stores */
        u32 pk0, pk1, pk2, pk3;
        {
            u16 h0 = f2bf_hi(hv.x); pk0 = (u32)h0 | ((u32)f2bf_hi(hv.x - bf2f(h0)) << 16);
            u16 h1 = f2bf_hi(hv.y); pk1 = (u32)h1 | ((u32)f2bf_hi(hv.y - bf2f(h1)) << 16);
            u16 h2 = f2bf_hi(hv.z); pk2 = (u32)h2 | ((u32)f2bf_hi(hv.z - bf2f(h2)) << 16);
            u16 h3 = f2bf_hi(hv.w); pk3 = (u32)h3 | ((u32)f2bf_hi(hv.w - bf2f(h3)) << 16);
        }
        u32* hp = hout + (size_t)brow * HD + j0;
        __hip_atomic_store(hp + 0, pk0, __ATOMIC_RELAXED, __HIP_MEMORY_SCOPE_AGENT);
        __hip_atomic_store(hp + 1, pk1, __ATOMIC_RELAXED, __HIP_MEMORY_SCOPE_AGENT);
        __hip_atomic_store(hp + 2, pk2, __ATOMIC_RELAXED, __HIP_MEMORY_SCOPE_AGENT);
        __hip_atomic_store(hp + 3, pk3, __ATOMIC_RELAXED, __HIP_MEMORY_SCOPE_AGENT);

        if (l == 9 && t == TT - 1)
            *(float4*)&out[(size_t)brow * ED + j0] = hv;

        /* barrier drains all waves' stores (vmcnt(0)), then one flag add */
        __syncthreads();
        if (tid == 0)
            __hip_atomic_fetch_add(&flg[((size_t)(l * TT + t) * 2 + bt) * 4], 1u,
                                   __ATOMIC_RELAXED, __HIP_MEMORY_SCOPE_AGENT);
    }
}

__global__ __launch_bounds__(512, 2) void lstm_persist(
    const float* __restrict__ b_1, const float* __restrict__ b_2,
    u32* __restrict__ wsd, float* __restrict__ out)
{
    __shared__ __align__(16) u16 A_sh[65536];   /* 128 KiB */

    const int bid = blockIdx.x;
    int l, jt, bt;
    if (bid < 32)       { l = 0;             jt = bid >> 1;              bt = bid & 1; }
    else if (bid < 160) { int r = bid - 32;  l = 1 + (r >> 5); r &= 31;  jt = r >> 1; bt = r & 1; }
    else if (bid < 176) { int r = bid - 160; l = 5;                      jt = r >> 1; bt = r & 1; }
    else                { int r = bid - 176; l = 6 + (r >> 4); r &= 15;  jt = r >> 1; bt = r & 1; }

    const int hd  = (l < 5) ? 256 : 128;
    const int din = (l == 0) ? 32 : ((l < 6) ? 256 : 128);
    const int nk  = (din + hd) >> 5;
    const float* bias = (l < 5) ? (b_1 + l * 1024) : (b_2 + (l - 5) * 512);

    u32* hbuf = wsd;
    u32* flg  = wsd + H_U32;
    const u32* xp = wsd + XP_OFF;
    const u16* wt = (const u16*)(wsd + WT_OFF);

    const int tid  = threadIdx.x;
    const int lane = tid & 63;
    const int wv   = tid >> 6;
    const int r15  = lane & 15;
    const int kq   = lane >> 4;
    const int brow = bt * 128 + wv * 16 + r15;
    const int j0   = jt * 16 + kq * 4;

    /* one-time: copy this block's fragment-ordered weight slice into LDS */
    {
        const uint4* src = (const uint4*)(wt + g_woff[l] + (size_t)jt * 8 * nk * 512);
        uint4* dst = (uint4*)A_sh;
        const int n4 = nk * 512;
        for (int i = tid; i < n4; i += 512) dst[i] = src[i];
    }
    __syncthreads();

    int oh0 = (0 * nk) * 512 + lane * 8, ol0 = (1 * nk) * 512 + lane * 8;
    int oh1 = (2 * nk) * 512 + lane * 8, ol1 = (3 * nk) * 512 + lane * 8;
    int oh2 = (4 * nk) * 512 + lane * 8, ol2 = (5 * nk) * 512 + lane * 8;
    int oh3 = (6 * nk) * 512 + lane * 8, ol3 = (7 * nk) * 512 + lane * 8;

    const u32 tgt_my = (l < 5) ? 16u : 8u;
    const u32 tgt_lo = (l > 0) ? ((l - 1 < 5) ? 16u : 8u) : 0u;
    const u32 tgt_dn = (l < 9) ? ((l + 1 < 5) ? 16u : 8u) : 0u;

    if (l == 0)
        run_all<1, 8, true >(l, bt, xp, bias, hbuf, flg, out, A_sh,
                             oh0,oh1,oh2,oh3, ol0,ol1,ol2,ol3,
                             brow, j0, kq, hd, tgt_lo, tgt_my, tgt_dn);
    else if (l < 5)
        run_all<8, 8, false>(l, bt, xp, bias, hbuf, flg, out, A_sh,
                             oh0,oh1,oh2,oh3, ol0,ol1,ol2,ol3,
                             brow, j0, kq, hd, tgt_lo, tgt_my, tgt_dn);
    else if (l == 5)
        run_all<8, 4, false>(l, bt, xp, bias, hbuf, flg, out, A_sh,
                             oh0,oh1,oh2,oh3, ol0,ol1,ol2,ol3,
                             brow, j0, kq, hd, tgt_lo, tgt_my, tgt_dn);
    else
        run_all<4, 4, false>(l, bt, xp, bias, hbuf, flg, out, A_sh,
                             oh0,oh1,oh2,oh3, ol0,ol1,ol2,ol3,
                             brow, j0, kq, hd, tgt_lo, tgt_my, tgt_dn);
}

extern "C" void kernel_launch(void* const* d_in, const int* in_sizes, int n_in,
                              void* d_out, int out_size, void* d_ws, size_t ws_size,
                              hipStream_t stream) {
    const float* x       = (const float*)d_in[0];
    const float* w_ih0_1 = (const float*)d_in[1];
    const float* w_ihr_1 = (const float*)d_in[2];
    const float* w_hh_1  = (const float*)d_in[3];
    const float* b_1     = (const float*)d_in[4];
    const float* w_ih0_2 = (const float*)d_in[5];
    const float* w_ihr_2 = (const float*)d_in[6];
    const float* w_hh_2  = (const float*)d_in[7];
    const float* b_2     = (const float*)d_in[8];
    u32*   wsd = (u32*)d_ws;
    float* out = (float*)d_out;

    hipLaunchKernelGGL(zero_state, dim3(512), dim3(256), 0, stream, wsd);
    hipLaunchKernelGGL(conv_all, dim3(1024), dim3(256), 0, stream,
                       w_ih0_1, w_ihr_1, w_hh_1, w_ih0_2, w_ihr_2, w_hh_2, wsd);
    hipLaunchKernelGGL(conv_x, dim3(256), dim3(256), 0, stream, x, wsd);
    hipLaunchKernelGGL(lstm_persist, dim3(240), dim3(512), 0, stream,
                       b_1, b_2, wsd, out);
}

// Round 7
// 5125.543 us; speedup vs baseline: 1.6743x; 1.6743x over previous
//
#include <hip/hip_runtime.h>
#include <math.h>

typedef unsigned short u16;
typedef unsigned int   u32;
typedef unsigned long long u64;
typedef __bf16 bf16x8 __attribute__((ext_vector_type(8)));
typedef float  f32x4  __attribute__((ext_vector_type(4)));

#define BB 256
#define TT 256
#define HD 256
#define ED 128
#define DEPTH 4

/* ws layout (u32 units):
   [0, H_U32)        : h slots, packed bf16 hi|lo<<16  [10][DEPTH][256][256]
   [H_U32, +FLG_U32) : flags [10][256][2] padded x4 (16B)
   [XP_OFF, +XP_U32) : packed x  [256][256][8]
   [WT_OFF, ...)     : fragment-ordered bf16 weights (r4-r6 proven layout)  */
#define H_U32   (10 * DEPTH * BB * HD)      /* 2,621,440 */
#define FLG_U32 (10 * TT * 2 * 4)           /*    20,480 */
#define XP_OFF  (H_U32 + FLG_U32)
#define XP_U32  (BB * TT * 8)               /*   524,288 */
#define WT_OFF  (XP_OFF + XP_U32)

__constant__ size_t g_woff[10] = {0ul,589824ul,1638400ul,2686976ul,3735552ul,
                                  4784128ul,5177344ul,5439488ul,5701632ul,5963776ul};
__constant__ int g_cb[11] = {0,73728,204800,335872,466944,598016,
                             647168,679936,712704,745472,778240};

__device__ __forceinline__ u16 f2bf_hi(float f) {
    u32 u = __float_as_uint(f);
    u32 r = (u + 0x7FFFu + ((u >> 16) & 1u)) >> 16;
    return (u16)r;
}
__device__ __forceinline__ float bf2f(u16 h) { return __uint_as_float(((u32)h) << 16); }
__device__ __forceinline__ float sigmoidf_(float v) { return 1.0f / (1.0f + expf(-v)); }

__global__ __launch_bounds__(256) void zero_state(u32* wsd) {
    const int n = H_U32 + FLG_U32;
    for (int i = blockIdx.x * blockDim.x + threadIdx.x; i < n; i += gridDim.x * blockDim.x)
        wsd[i] = 0u;
}

__global__ __launch_bounds__(256) void conv_x(const float* __restrict__ x, u32* __restrict__ wsd) {
    u32* xp = wsd + XP_OFF;
    for (int i = blockIdx.x * blockDim.x + threadIdx.x; i < XP_U32; i += gridDim.x * blockDim.x) {
        float v = x[i];
        u16 hi = f2bf_hi(v);
        u16 lo = f2bf_hi(v - bf2f(hi));
        xp[i] = (u32)hi | ((u32)lo << 16);
    }
}

/* weights -> bf16 hi/lo, MFMA fragment order (identical to rounds 4-6) */
__global__ __launch_bounds__(256) void conv_all(
    const float* __restrict__ w_ih0_1, const float* __restrict__ w_ihr_1,
    const float* __restrict__ w_hh_1,
    const float* __restrict__ w_ih0_2, const float* __restrict__ w_ihr_2,
    const float* __restrict__ w_hh_2,
    u32* __restrict__ wsd)
{
    __bf16* dst0 = (__bf16*)(wsd + WT_OFF);
    const int nch = 778240;
    for (int ci = blockIdx.x * blockDim.x + threadIdx.x; ci < nch;
         ci += gridDim.x * blockDim.x) {
        int l = 0;
        while (ci >= g_cb[l + 1]) ++l;
        int di = ci - g_cb[l];

        const int hd  = (l < 5) ? 256 : 128;
        const int din = (l == 0) ? 32 : ((l < 6) ? 256 : 128);
        const int xw  = (l == 0) ? 8 : din;
        const int Kp  = din + hd;
        const int nk  = Kp >> 5;

        const float *wih, *whh; int wihld, whhld;
        if (l == 0)      { wih = w_ih0_1;                                whh = w_hh_1;
                           wihld = 8;   whhld = 256; }
        else if (l < 5)  { wih = w_ihr_1 + (size_t)(l - 1) * 1024 * 256; whh = w_hh_1 + (size_t)l * 1024 * 256;
                           wihld = 256; whhld = 256; }
        else if (l == 5) { wih = w_ih0_2;                                whh = w_hh_2;
                           wihld = 256; whhld = 128; }
        else             { wih = w_ihr_2 + (size_t)(l - 6) * 512 * 128;  whh = w_hh_2 + (size_t)(l - 5) * 512 * 128;
                           wihld = 128; whhld = 128; }

        int lane = di & 63;
        int rem  = di >> 6;
        int kt   = rem % nk;
        int rem2 = rem / nk;
        int p    = rem2 & 1;
        int g    = (rem2 >> 1) & 3;
        int jt   = rem2 >> 3;
        int r15  = lane & 15, kq = lane >> 4;
        int row  = g * hd + jt * 16 + r15;

        bf16x8 o8;
        #pragma unroll
        for (int e = 0; e < 8; ++e) {
            int k = kt * 32 + kq * 8 + e;
            float v = 0.0f;
            if (k < xw) v = wih[(size_t)row * wihld + k];
            else if (k >= din && k < Kp) v = whh[(size_t)row * whhld + (k - din)];
            __bf16 h = (__bf16)v;
            o8[e] = p ? (__bf16)(v - (float)h) : h;
        }
        *(bf16x8*)(dst0 + g_woff[l] + (size_t)di * 8) = o8;
    }
}

struct U64x8 { u64 q[8]; };

__device__ __forceinline__ void unpack4(const u64* q, bf16x8& bh, bf16x8& bl) {
    union { u64 q2[4]; u32 w[8]; } U;
    U.q2[0] = q[0]; U.q2[1] = q[1]; U.q2[2] = q[2]; U.q2[3] = q[3];
    union { u32 u[4]; bf16x8 v; } H, L;
    #pragma unroll
    for (int i = 0; i < 4; ++i) {
        u32 a = U.w[2 * i], b = U.w[2 * i + 1];
        H.u[i] = (a & 0xFFFFu) | (b << 16);
        L.u[i] = (a >> 16) | (b & 0xFFFF0000u);
    }
    bh = H.v; bl = L.v;
}

__device__ __forceinline__ int fidx(int l_, int t_, int bt_) {
    return ((l_ * TT + t_) * 2 + bt_) * 4;
}

template<int NKI, int NKR, bool ISL0>
__device__ void run_all(
    int l, int jt, int bt, int hd,
    const u32* __restrict__ xp, const float* __restrict__ bias,
    u32* __restrict__ hbuf, u32* __restrict__ flg, float* __restrict__ out,
    const u16* __restrict__ A_sh)
{
    constexpr int NKT = NKI + NKR;
    constexpr int DIN = NKI * 32;
    const int tid  = threadIdx.x;
    const int lane = tid & 63;
    const int wv   = tid >> 6;                 /* 0..3 */
    const int r15  = lane & 15;
    const int kq   = lane >> 4;
    const int brow0 = bt * 128 + wv * 32 + r15;    /* btile0; btile1 = +16 */
    const int j0   = jt * 16 + kq * 4;

    int offH[4], offL[4];
    #pragma unroll
    for (int g = 0; g < 4; ++g) {
        offH[g] = (g * 2)     * NKT * 512 + lane * 8;
        offL[g] = (g * 2 + 1) * NKT * 512 + lane * 8;
    }

    float bias_r[4][4];
    #pragma unroll
    for (int g = 0; g < 4; ++g) {
        float4 v = *(const float4*)&bias[g * hd + j0];
        bias_r[g][0] = v.x; bias_r[g][1] = v.y; bias_r[g][2] = v.z; bias_r[g][3] = v.w;
    }

    float4 cv0 = make_float4(0.f,0.f,0.f,0.f);
    float4 cv1 = make_float4(0.f,0.f,0.f,0.f);

    const u32 NJT_MY = (l < 5) ? 16u : 8u;
    const u32 NJT_LO = ((l - 1) < 5) ? 16u : 8u;
    const u32 NJT_DN = ((l + 1) < 5) ? 16u : 8u;

    for (int t = 0; t < TT; ++t) {
        /* ---- sync: wave0 lanes 0-2 poll the 3 deps in parallel ---- */
        if (wv == 0) {
            const u32* ap = nullptr; u32 tg = 0;
            if (lane == 0 && !ISL0)                 { ap = flg + fidx(l - 1, t, bt);       tg = NJT_LO; }
            if (lane == 1 && t > 0)                 { ap = flg + fidx(l, t - 1, bt);       tg = NJT_MY; }
            if (lane == 2 && l < 9 && t >= DEPTH)   { ap = flg + fidx(l + 1, t - DEPTH, bt); tg = NJT_DN; }
            bool pend = (ap != nullptr);
            for (int it = 0; it < (1 << 18); ++it) {
                if (pend && __hip_atomic_load(ap, __ATOMIC_RELAXED, __HIP_MEMORY_SCOPE_AGENT) >= tg)
                    pend = false;
                if (!__any(pend)) break;
                __builtin_amdgcn_s_sleep(1);
            }
        }
        __syncthreads();

        const u32* hin   = hbuf + ((size_t)(l - 1) * DEPTH + (t & (DEPTH - 1))) * (BB * HD);
        const u32* hprev = hbuf + ((size_t)l * DEPTH + ((t - 1) & (DEPTH - 1))) * (BB * HD);
        u32*       hout  = hbuf + ((size_t)l * DEPTH + (t & (DEPTH - 1))) * (BB * HD);

        auto loadB = [&](int kt, U64x8& v) {
            if constexpr (ISL0) {
                if (kt == 0) {
                    if (kq == 0) {
                        const u32* p0 = xp + ((size_t)brow0 * TT + t) * 8;
                        const u32* p1 = xp + ((size_t)(brow0 + 16) * TT + t) * 8;
                        #pragma unroll
                        for (int i = 0; i < 4; ++i) {
                            v.q[i]     = *((const u64*)p0 + i);
                            v.q[4 + i] = *((const u64*)p1 + i);
                        }
                    } else {
                        #pragma unroll
                        for (int i = 0; i < 8; ++i) v.q[i] = 0ull;
                    }
                } else {
                    int k0 = kt * 32 - 32 + kq * 8;
                    const u64* p0 = (const u64*)(hprev + (size_t)brow0 * HD + k0);
                    const u64* p1 = (const u64*)(hprev + (size_t)(brow0 + 16) * HD + k0);
                    #pragma unroll
                    for (int i = 0; i < 4; ++i) {
                        v.q[i]     = __hip_atomic_load(p0 + i, __ATOMIC_RELAXED, __HIP_MEMORY_SCOPE_AGENT);
                        v.q[4 + i] = __hip_atomic_load(p1 + i, __ATOMIC_RELAXED, __HIP_MEMORY_SCOPE_AGENT);
                    }
                }
            } else {
                const u32* base = (kt < NKI) ? hin : hprev;
                int k0 = (kt < NKI) ? (kt * 32 + kq * 8) : (kt * 32 - DIN + kq * 8);
                const u64* p0 = (const u64*)(base + (size_t)brow0 * HD + k0);
                const u64* p1 = (const u64*)(base + (size_t)(brow0 + 16) * HD + k0);
                #pragma unroll
                for (int i = 0; i < 4; ++i) {
                    v.q[i]     = __hip_atomic_load(p0 + i, __ATOMIC_RELAXED, __HIP_MEMORY_SCOPE_AGENT);
                    v.q[4 + i] = __hip_atomic_load(p1 + i, __ATOMIC_RELAXED, __HIP_MEMORY_SCOPE_AGENT);
                }
            }
        };

        f32x4 acc[4][2];
        #pragma unroll
        for (int g = 0; g < 4; ++g) { acc[g][0] = (f32x4){0.f,0.f,0.f,0.f}; acc[g][1] = (f32x4){0.f,0.f,0.f,0.f}; }

        /* 3-deep B prefetch covers ~800cy L3 latency */
        U64x8 b0, b1, b2, b3;
        loadB(0, b0);
        if (NKT > 1) loadB(1, b1);
        if (NKT > 2) loadB(2, b2);
        #pragma unroll
        for (int kt = 0; kt < NKT; ++kt) {
            if (kt + 3 < NKT) loadB(kt + 3, b3);
            bf16x8 bh0, bl0, bh1, bl1;
            unpack4(&b0.q[0], bh0, bl0);
            unpack4(&b0.q[4], bh1, bl1);
            const int kof = kt * 512;
            #pragma unroll
            for (int g = 0; g < 4; ++g) {
                bf16x8 ah = *(const bf16x8*)&A_sh[offH[g] + kof];
                bf16x8 al = *(const bf16x8*)&A_sh[offL[g] + kof];
                acc[g][0] = __builtin_amdgcn_mfma_f32_16x16x32_bf16(ah, bh0, acc[g][0], 0,0,0);
                acc[g][1] = __builtin_amdgcn_mfma_f32_16x16x32_bf16(ah, bh1, acc[g][1], 0,0,0);
                acc[g][0] = __builtin_amdgcn_mfma_f32_16x16x32_bf16(ah, bl0, acc[g][0], 0,0,0);
                acc[g][1] = __builtin_amdgcn_mfma_f32_16x16x32_bf16(ah, bl1, acc[g][1], 0,0,0);
                acc[g][0] = __builtin_amdgcn_mfma_f32_16x16x32_bf16(al, bh0, acc[g][0], 0,0,0);
                acc[g][1] = __builtin_amdgcn_mfma_f32_16x16x32_bf16(al, bh1, acc[g][1], 0,0,0);
            }
            b0 = b1; b1 = b2; b2 = b3;
        }

        /* ---- epilogue: both batch tiles, c in registers ---- */
        #pragma unroll
        for (int bti = 0; bti < 2; ++bti) {
            float4& cv = bti ? cv1 : cv0;
            const int brow = brow0 + bti * 16;
            float4 hv;
            {
                float i_, f_, g_, o_;
                i_ = sigmoidf_(acc[0][bti][0] + bias_r[0][0]); f_ = sigmoidf_(acc[1][bti][0] + bias_r[1][0]);
                g_ = tanhf   (acc[2][bti][0] + bias_r[2][0]); o_ = sigmoidf_(acc[3][bti][0] + bias_r[3][0]);
                cv.x = fmaf(f_, cv.x, i_ * g_); hv.x = o_ * tanhf(cv.x);
                i_ = sigmoidf_(acc[0][bti][1] + bias_r[0][1]); f_ = sigmoidf_(acc[1][bti][1] + bias_r[1][1]);
                g_ = tanhf   (acc[2][bti][1] + bias_r[2][1]); o_ = sigmoidf_(acc[3][bti][1] + bias_r[3][1]);
                cv.y = fmaf(f_, cv.y, i_ * g_); hv.y = o_ * tanhf(cv.y);
                i_ = sigmoidf_(acc[0][bti][2] + bias_r[0][2]); f_ = sigmoidf_(acc[1][bti][2] + bias_r[1][2]);
                g_ = tanhf   (acc[2][bti][2] + bias_r[2][2]); o_ = sigmoidf_(acc[3][bti][2] + bias_r[3][2]);
                cv.z = fmaf(f_, cv.z, i_ * g_); hv.z = o_ * tanhf(cv.z);
                i_ = sigmoidf_(acc[0][bti][3] + bias_r[0][3]); f_ = sigmoidf_(acc[1][bti][3] + bias_r[1][3]);
                g_ = tanhf   (acc[2][bti][3] + bias_r[2][3]); o_ = sigmoidf_(acc[3][bti][3] + bias_r[3][3]);
                cv.w = fmaf(f_, cv.w, i_ * g_); hv.w = o_ * tanhf(cv.w);
            }
            u32 pk0, pk1, pk2, pk3;
            {
                u16 h0 = f2bf_hi(hv.x); pk0 = (u32)h0 | ((u32)f2bf_hi(hv.x - bf2f(h0)) << 16);
                u16 h1 = f2bf_hi(hv.y); pk1 = (u32)h1 | ((u32)f2bf_hi(hv.y - bf2f(h1)) << 16);
                u16 h2 = f2bf_hi(hv.z); pk2 = (u32)h2 | ((u32)f2bf_hi(hv.z - bf2f(h2)) << 16);
                u16 h3 = f2bf_hi(hv.w); pk3 = (u32)h3 | ((u32)f2bf_hi(hv.w - bf2f(h3)) << 16);
            }
            u64* hp = (u64*)(hout + (size_t)brow * HD + j0);
            __hip_atomic_store(hp + 0, (u64)pk0 | ((u64)pk1 << 32), __ATOMIC_RELAXED, __HIP_MEMORY_SCOPE_AGENT);
            __hip_atomic_store(hp + 1, (u64)pk2 | ((u64)pk3 << 32), __ATOMIC_RELAXED, __HIP_MEMORY_SCOPE_AGENT);
            if (l == 9 && t == TT - 1)
                *(float4*)&out[(size_t)brow * ED + j0] = hv;
        }

        /* barrier drains all waves' stores (vmcnt 0), then one flag add */
        __syncthreads();
        if (tid == 0)
            __hip_atomic_fetch_add(flg + fidx(l, t, bt), 1u,
                                   __ATOMIC_RELAXED, __HIP_MEMORY_SCOPE_AGENT);
    }
}

/* Persistent kernel: 240 blocks (1/CU), 256 thr = 4 waves x 32 batches.
   W (hi+lo, fragment order) in LDS; c in registers; h via write-through
   atomic stores + L3-direct atomic loads; NO fences anywhere. */
__global__ __launch_bounds__(256, 1) void lstm_persist(
    const float* __restrict__ b_1, const float* __restrict__ b_2,
    u32* __restrict__ wsd, float* __restrict__ out)
{
    __shared__ __align__(16) u16 A_sh[65536];   /* 128 KiB */

    const int bid = blockIdx.x;
    int l, jt, bt;
    if (bid < 32)       { l = 0;             jt = bid >> 1;              bt = bid & 1; }
    else if (bid < 160) { int r = bid - 32;  l = 1 + (r >> 5); r &= 31;  jt = r >> 1; bt = r & 1; }
    else if (bid < 176) { int r = bid - 160; l = 5;                      jt = r >> 1; bt = r & 1; }
    else                { int r = bid - 176; l = 6 + (r >> 4); r &= 15;  jt = r >> 1; bt = r & 1; }

    const int hd  = (l < 5) ? 256 : 128;
    const int din = (l == 0) ? 32 : ((l < 6) ? 256 : 128);
    const int nk  = (din + hd) >> 5;
    const float* bias = (l < 5) ? (b_1 + l * 1024) : (b_2 + (l - 5) * 512);

    u32* hbuf = wsd;
    u32* flg  = wsd + H_U32;
    const u32* xp = wsd + XP_OFF;
    const u16* wt = (const u16*)(wsd + WT_OFF);

    /* one-time: copy this block's fragment-ordered weight slice into LDS */
    {
        const uint4* src = (const uint4*)(wt + g_woff[l] + (size_t)jt * 8 * nk * 512);
        uint4* dst = (uint4*)A_sh;
        const int n4 = nk * 512;
        for (int i = threadIdx.x; i < n4; i += 256) dst[i] = src[i];
    }
    __syncthreads();

    if (l == 0)
        run_all<1, 8, true >(l, jt, bt, hd, xp, bias, hbuf, flg, out, A_sh);
    else if (l < 5)
        run_all<8, 8, false>(l, jt, bt, hd, xp, bias, hbuf, flg, out, A_sh);
    else if (l == 5)
        run_all<8, 4, false>(l, jt, bt, hd, xp, bias, hbuf, flg, out, A_sh);
    else
        run_all<4, 4, false>(l, jt, bt, hd, xp, bias, hbuf, flg, out, A_sh);
}

extern "C" void kernel_launch(void* const* d_in, const int* in_sizes, int n_in,
                              void* d_out, int out_size, void* d_ws, size_t ws_size,
                              hipStream_t stream) {
    const float* x       = (const float*)d_in[0];
    const float* w_ih0_1 = (const float*)d_in[1];
    const float* w_ihr_1 = (const float*)d_in[2];
    const float* w_hh_1  = (const float*)d_in[3];
    const float* b_1     = (const float*)d_in[4];
    const float* w_ih0_2 = (const float*)d_in[5];
    const float* w_ihr_2 = (const float*)d_in[6];
    const float* w_hh_2  = (const float*)d_in[7];
    const float* b_2     = (const float*)d_in[8];
    u32*   wsd = (u32*)d_ws;
    float* out = (float*)d_out;

    hipLaunchKernelGGL(zero_state, dim3(1024), dim3(256), 0, stream, wsd);
    hipLaunchKernelGGL(conv_all, dim3(1024), dim3(256), 0, stream,
                       w_ih0_1, w_ihr_1, w_hh_1, w_ih0_2, w_ihr_2, w_hh_2, wsd);
    hipLaunchKernelGGL(conv_x, dim3(256), dim3(256), 0, stream, x, wsd);
    hipLaunchKernelGGL(lstm_persist, dim3(240), dim3(256), 0, stream,
                       b_1, b_2, wsd, out);
}